// Round 2
// baseline (16014.165 us; speedup 1.0000x reference)
//
#include <hip/hip_runtime.h>
#include <hip/hip_cooperative_groups.h>
#include <math.h>

namespace cg = cooperative_groups;

typedef unsigned short u16;
typedef __bf16 bf16x8 __attribute__((ext_vector_type(8)));
typedef float f32x4 __attribute__((ext_vector_type(4)));
typedef unsigned short u16x8 __attribute__((ext_vector_type(8)));

#define NBLK 256
#define NTHR 256
#define BB 1024
#define TT 256
#define EE 512
#define UU 1024
#define K0 1536          // [emb(512) | h0(1024)]
#define K1 2048          // [h0'(1024) | h1(1024)]
#define LDS_BYTES (32 * K1 * 2)   // 128 KB: one 32-col B stripe, fragment-swizzled

__device__ __forceinline__ u16 f2bf(float f) {
  unsigned u = __builtin_bit_cast(unsigned, f);
  u += 0x7fffu + ((u >> 16) & 1u);
  return (u16)(u >> 16);
}
__device__ __forceinline__ float bf2f(u16 h) {
  return __builtin_bit_cast(float, ((unsigned)h) << 16);
}
__device__ __forceinline__ float fast_tanh(float x) {
  x = fminf(fmaxf(x, -15.f), 15.f);
  float e = __expf(2.f * x);
  return (e - 1.f) / (e + 1.f);
}

// ---- weight transpose + fragment swizzle: Wt[g*8+e], g=((cg*2+ct)*NK+kt)*64+lane
// value = Wfull[k][n], n = cg*32+ct*16+(lane&15), k = kt*32+(lane>>4)*8+e
template<int K, int KLOW>
__device__ __forceinline__ void wfill(u16* __restrict__ Wt,
    const float* __restrict__ Wl, const float* __restrict__ Wh, int gstart) {
  constexpr int NK = K / 32;
  constexpr int NG = 1024 * K / 8;
  for (int g = gstart; g < NG; g += NBLK * NTHR) {
    const int lane = g & 63;
    const int r = g >> 6;
    const int kt = r % NK;
    const int cc = r / NK;
    const int n = (cc >> 1) * 32 + (cc & 1) * 16 + (lane & 15);
    const int kb = kt * 32 + (lane >> 4) * 8;
    u16x8 o;
#pragma unroll
    for (int e = 0; e < 8; ++e) {
      const int k = kb + e;
      const float v = (k < KLOW) ? Wl[(size_t)k * UU + n] : Wh[(size_t)(k - KLOW) * UU + n];
      o[e] = f2bf(v);
    }
    *(u16x8*)(Wt + (size_t)g * 8) = o;
  }
}

// ---- one tick of one flavor: C[256x32] = A[256xK] @ Bt, tanh, bf16 out (1 or 2 dests)
template<int K, bool DUAL>
__device__ __forceinline__ void gemm_tick(const u16* __restrict__ A, const u16* __restrict__ B,
    const float* __restrict__ bias, int M0, int N0, int tid,
    u16* __restrict__ out0, int ld0, u16* __restrict__ out1, int ld1) {
  constexpr int NK = K / 32;
  const int lane = tid & 63, w = tid >> 6, q = lane >> 4, l16 = lane & 15;
  const u16* ar0 = A + (size_t)(M0 + w * 64 + l16) * K + q * 8;
  const u16* bb = B + lane * 8;

  f32x4 acc[4][2];
#pragma unroll
  for (int i = 0; i < 4; ++i)
#pragma unroll
    for (int j = 0; j < 2; ++j) acc[i][j] = (f32x4){0.f, 0.f, 0.f, 0.f};

#pragma unroll 4
  for (int kt = 0; kt < NK; ++kt) {
    u16x8 a0 = *(const u16x8*)(ar0 + kt * 32);
    u16x8 a1 = *(const u16x8*)(ar0 + (size_t)16 * K + kt * 32);
    u16x8 a2 = *(const u16x8*)(ar0 + (size_t)32 * K + kt * 32);
    u16x8 a3 = *(const u16x8*)(ar0 + (size_t)48 * K + kt * 32);
    u16x8 b0 = *(const u16x8*)(bb + kt * 512);
    u16x8 b1 = *(const u16x8*)(bb + (NK + kt) * 512);
    bf16x8 fb0 = __builtin_bit_cast(bf16x8, b0);
    bf16x8 fb1 = __builtin_bit_cast(bf16x8, b1);
    acc[0][0] = __builtin_amdgcn_mfma_f32_16x16x32_bf16(__builtin_bit_cast(bf16x8, a0), fb0, acc[0][0], 0, 0, 0);
    acc[0][1] = __builtin_amdgcn_mfma_f32_16x16x32_bf16(__builtin_bit_cast(bf16x8, a0), fb1, acc[0][1], 0, 0, 0);
    acc[1][0] = __builtin_amdgcn_mfma_f32_16x16x32_bf16(__builtin_bit_cast(bf16x8, a1), fb0, acc[1][0], 0, 0, 0);
    acc[1][1] = __builtin_amdgcn_mfma_f32_16x16x32_bf16(__builtin_bit_cast(bf16x8, a1), fb1, acc[1][1], 0, 0, 0);
    acc[2][0] = __builtin_amdgcn_mfma_f32_16x16x32_bf16(__builtin_bit_cast(bf16x8, a2), fb0, acc[2][0], 0, 0, 0);
    acc[2][1] = __builtin_amdgcn_mfma_f32_16x16x32_bf16(__builtin_bit_cast(bf16x8, a2), fb1, acc[2][1], 0, 0, 0);
    acc[3][0] = __builtin_amdgcn_mfma_f32_16x16x32_bf16(__builtin_bit_cast(bf16x8, a3), fb0, acc[3][0], 0, 0, 0);
    acc[3][1] = __builtin_amdgcn_mfma_f32_16x16x32_bf16(__builtin_bit_cast(bf16x8, a3), fb1, acc[3][1], 0, 0, 0);
  }

  const float bs0 = bias[N0 + l16];
  const float bs1 = bias[N0 + 16 + l16];
#pragma unroll
  for (int i = 0; i < 4; ++i) {
#pragma unroll
    for (int rr = 0; rr < 4; ++rr) {
      const int row = M0 + w * 64 + i * 16 + q * 4 + rr;
      const u16 v0 = f2bf(fast_tanh(acc[i][0][rr] + bs0));
      const u16 v1 = f2bf(fast_tanh(acc[i][1][rr] + bs1));
      out0[(size_t)row * ld0 + l16] = v0;
      out0[(size_t)row * ld0 + 16 + l16] = v1;
      if (DUAL) {
        out1[(size_t)row * ld1 + l16] = v0;
        out1[(size_t)row * ld1 + 16 + l16] = v1;
      }
    }
  }
}

__global__ __launch_bounds__(NTHR, 1)
void rnn_kernel(const int* __restrict__ inputs, const float* __restrict__ emb,
    const float* __restrict__ W0, const float* __restrict__ U0, const float* __restrict__ b0,
    const float* __restrict__ W1, const float* __restrict__ U1, const float* __restrict__ b1,
    const float* __restrict__ Wout, const float* __restrict__ bout,
    float* __restrict__ out,
    u16* __restrict__ Wt0, u16* __restrict__ Wt1,
    u16* __restrict__ A0, u16* __restrict__ A1)
{
  extern __shared__ u16 lds[];
  cg::grid_group grid = cg::this_grid();
  const int tid = threadIdx.x, bid = blockIdx.x;
  const int xcd = bid & 7;
  const int flavor = (xcd >= 4);          // XCD 0-3: layer0, XCD 4-7: layer1
  const int rg = xcd & 3;                 // row group -> batch slice L2-local per XCD
  const int cgrp = bid >> 3;              // 0..31 column group (32 cols)
  const int M0 = rg * 256, N0 = cgrp * 32;
  const size_t HN0 = (size_t)BB * K0, HN1 = (size_t)BB * K1;

  // ---- startup: weight swizzle, emb(0), zero h0(-1)/h1(-1) ----
  const int gstart = bid * NTHR + tid;
  wfill<K0, 512>(Wt0, W0, U0, gstart);
  wfill<K1, 1024>(Wt1, W1, U1, gstart);
  for (int g = gstart; g < BB * EE / 8; g += NBLK * NTHR) {   // emb(t=0) -> A0 buf0 cols 0..511
    const int b = g >> 6, seg = g & 63;
    const int idx = inputs[b * TT];
    const f32x4* s = (const f32x4*)(emb + (size_t)idx * EE + seg * 8);
    f32x4 f0 = s[0], f1 = s[1];
    u16x8 o;
#pragma unroll
    for (int j = 0; j < 4; ++j) { o[j] = f2bf(f0[j]); o[j + 4] = f2bf(f1[j]); }
    *(u16x8*)(A0 + (size_t)b * K0 + seg * 8) = o;
  }
  {
    const u16x8 z = {0, 0, 0, 0, 0, 0, 0, 0};
    for (int g = gstart; g < BB * 1024 / 8; g += NBLK * NTHR) {
      const int b = g >> 7, seg = g & 127;
      *(u16x8*)(A0 + (size_t)b * K0 + 512 + seg * 8) = z;     // h0(-1) = 0
      *(u16x8*)(A1 + (size_t)b * K1 + 1024 + seg * 8) = z;    // h1(-1) = 0
    }
  }
  grid.sync();

  // ---- load my B stripe into LDS (fragment-swizzled, conflict-free reads) ----
  {
    const int Kf = flavor ? K1 : K0;
    const u16x8* s = (const u16x8*)((flavor ? Wt1 : Wt0) + (size_t)cgrp * 32 * Kf);
    u16x8* d = (u16x8*)lds;
    const int nv = 32 * Kf / 8;
    for (int i = tid; i < nv; i += NTHR) d[i] = s[i];
  }
  __syncthreads();

  // ---- pipelined tick loop: flavor0 does step tk, flavor1 does step tk-1 ----
  for (int tk = 0; tk <= TT; ++tk) {
    if (!flavor) {
      if (tk < TT) {
        const u16* Ain = A0 + (size_t)(tk & 1) * HN0;
        u16* o0 = A1 + (size_t)(tk & 1) * HN1 + N0;                 // h0'(tk) for layer1
        u16* o1 = A0 + (size_t)((tk + 1) & 1) * HN0 + 512 + N0;     // h0'(tk) for next layer0
        gemm_tick<K0, true>(Ain, lds, b0, M0, N0, tid, o0, K1, o1, K0);
      }
      if (tk < TT - 1) {   // convert emb(tk+1) -> A0[(tk+1)&1] cols 0..511
        u16* dst = A0 + (size_t)((tk + 1) & 1) * HN0;
        const int fid = rg * 32 + cgrp;               // 0..127
        const int row = fid * 8 + (tid >> 5);
        const int c = (tid & 31) * 16;
        const int idx = inputs[row * TT + tk + 1];
        const f32x4* s = (const f32x4*)(emb + (size_t)idx * EE + c);
        f32x4 f0 = s[0], f1 = s[1], f2 = s[2], f3 = s[3];
        u16x8 oa, ob;
#pragma unroll
        for (int j = 0; j < 4; ++j) {
          oa[j] = f2bf(f0[j]); oa[j + 4] = f2bf(f1[j]);
          ob[j] = f2bf(f2[j]); ob[j + 4] = f2bf(f3[j]);
        }
        *(u16x8*)(dst + (size_t)row * K0 + c) = oa;
        *(u16x8*)(dst + (size_t)row * K0 + c + 8) = ob;
      }
    } else {
      if (tk >= 1) {
        const u16* Ain = A1 + (size_t)((tk - 1) & 1) * HN1;
        u16* o0 = A1 + (size_t)(tk & 1) * HN1 + 1024 + N0;          // h1(tk-1)
        gemm_tick<K1, false>(Ain, lds, b1, M0, N0, tid, o0, K1, (u16*)nullptr, 0);
      }
    }
    grid.sync();
  }

  // ---- output: sigmoid(h1(255) @ Wout + bout); h1(255) in A1 buf0 cols 1024+ ----
  if (bid < 16) {
    const u16* hf = A1 + 1024;
    const int w = tid >> 6, lane = tid & 63;
    int m = (bid * 4 + w) * 16;
    for (int rr = 0; rr < 16; ++rr, ++m) {
      const u16x8* hv = (const u16x8*)(hf + (size_t)m * K1 + lane * 16);
      u16x8 lo = hv[0], hi = hv[1];
      const f32x4* wv = (const f32x4*)(Wout + lane * 16);
      f32x4 w0 = wv[0], w1 = wv[1], w2 = wv[2], w3 = wv[3];
      float s = 0.f;
#pragma unroll
      for (int j = 0; j < 4; ++j) {
        s += bf2f(lo[j]) * w0[j];
        s += bf2f(lo[j + 4]) * w1[j];
        s += bf2f(hi[j]) * w2[j];
        s += bf2f(hi[j + 4]) * w3[j];
      }
#pragma unroll
      for (int off = 32; off > 0; off >>= 1) s += __shfl_down(s, off);
      if (lane == 0) out[m] = 1.f / (1.f + expf(-(s + bout[0])));
    }
  }
}

extern "C" void kernel_launch(void* const* d_in, const int* in_sizes, int n_in,
                              void* d_out, int out_size, void* d_ws, size_t ws_size,
                              hipStream_t stream)
{
  (void)in_sizes; (void)n_in; (void)out_size; (void)ws_size;
  const int*   inputs = (const int*)d_in[0];
  const float* emb    = (const float*)d_in[1];
  const float* W0     = (const float*)d_in[2];
  const float* U0     = (const float*)d_in[3];
  const float* b0     = (const float*)d_in[4];
  const float* W1     = (const float*)d_in[5];
  const float* U1     = (const float*)d_in[6];
  const float* b1     = (const float*)d_in[7];
  const float* Wout   = (const float*)d_in[8];
  const float* bout   = (const float*)d_in[9];
  float* out = (float*)d_out;

  // ws (u16): Wt0 [1024*1536], Wt1 [1024*2048], A0 [2][1024*1536], A1 [2][1024*2048]
  u16* Wt0 = (u16*)d_ws;
  u16* Wt1 = Wt0 + (size_t)1024 * K0;
  u16* A0  = Wt1 + (size_t)1024 * K1;
  u16* A1  = A0 + (size_t)2 * 1024 * K0;

  static int lds_set = 0;
  if (!lds_set) {
    hipFuncSetAttribute((const void*)rnn_kernel,
                        hipFuncAttributeMaxDynamicSharedMemorySize, LDS_BYTES);
    lds_set = 1;
  }

  void* args[] = { &inputs, &emb, &W0, &U0, &b0, &W1, &U1, &b1, &Wout, &bout,
                   &out, &Wt0, &Wt1, &A0, &A1 };
  hipLaunchCooperativeKernel((void*)rnn_kernel, dim3(NBLK), dim3(NTHR), args, LDS_BYTES, stream);
}

// Round 3
// 9280.501 us; speedup vs baseline: 1.7256x; 1.7256x over previous
//
#include <hip/hip_runtime.h>
#include <hip/hip_cooperative_groups.h>
#include <math.h>

namespace cg = cooperative_groups;

typedef unsigned short u16;
typedef __bf16 bf16x8 __attribute__((ext_vector_type(8)));
typedef float f32x4 __attribute__((ext_vector_type(4)));
typedef unsigned short u16x8 __attribute__((ext_vector_type(8)));
typedef int i32x4 __attribute__((ext_vector_type(4)));

#define NBLK 256
#define NTHR 256
#define BB 1024
#define TT 256
#define EE 512
#define UU 1024
#define K0 1536          // A0 row: [emb(512) | h0(1024)]
#define K1 2048          // A1 row: [h0'(1024) | h1(1024)]
#define LDS_BYTES (32 * K1 * 2)   // 128 KB B stripe, fragment-swizzled

// barrier area (ints) at end of ws: arrive[256], epoch @256, roster @264..271
#define EPOCH_SLOT 256
#define ROSTER_SLOT 264
#define BAR_INTS 288

// gfx950 cache policy bits: sc0=1, nt=2, sc1=16
#define AUX_L2   1      // bypass L1, served by (same-XCD) L2
#define AUX_L3   17     // sc0|sc1: bypass L1+L2, coherent at L3

__device__ i32x4 llvm_amdgcn_raw_buffer_load_i32x4(i32x4 srsrc, int voffset, int soffset,
                                                   int aux) __asm("llvm.amdgcn.raw.buffer.load.v4i32");
__device__ void llvm_amdgcn_raw_buffer_store_i16(u16 vdata, i32x4 srsrc, int voffset, int soffset,
                                                 int aux) __asm("llvm.amdgcn.raw.buffer.store.i16");

__device__ __forceinline__ i32x4 make_srd(const void* p) {
  union { const void* p; int i[2]; } u; u.p = p;
  i32x4 r; r.x = u.i[0]; r.y = u.i[1]; r.z = -1; r.w = 0x00020000;
  return r;
}

__device__ __forceinline__ u16 f2bf(float f) {
  unsigned u = __builtin_bit_cast(unsigned, f);
  u += 0x7fffu + ((u >> 16) & 1u);
  return (u16)(u >> 16);
}
__device__ __forceinline__ float bf2f(u16 h) {
  return __builtin_bit_cast(float, ((unsigned)h) << 16);
}
__device__ __forceinline__ float fast_tanh(float x) {
  x = fminf(fmaxf(x, -15.f), 15.f);
  float e = __expf(2.f * x);
  return (e - 1.f) / (e + 1.f);
}

// weight transpose + MFMA-fragment swizzle (same mapping as round 2, verified)
template<int K, int KLOW>
__device__ __forceinline__ void wfill(u16* __restrict__ Wt,
    const float* __restrict__ Wl, const float* __restrict__ Wh, int gstart) {
  constexpr int NK = K / 32;
  constexpr int NG = 1024 * K / 8;
  for (int g = gstart; g < NG; g += NBLK * NTHR) {
    const int lane = g & 63;
    const int r = g >> 6;
    const int kt = r % NK;
    const int cc = r / NK;
    const int n = (cc >> 1) * 32 + (cc & 1) * 16 + (lane & 15);
    const int kb = kt * 32 + (lane >> 4) * 8;
    u16x8 o;
#pragma unroll
    for (int e = 0; e < 8; ++e) {
      const int k = kb + e;
      const float v = (k < KLOW) ? Wl[(size_t)k * UU + n] : Wh[(size_t)(k - KLOW) * UU + n];
      o[e] = f2bf(v);
    }
    *(u16x8*)(Wt + (size_t)g * 8) = o;
  }
}

template<int K, int AUX>
__device__ __forceinline__ void kstep(const i32x4& srdA, int voA, int kt,
                                      const u16* __restrict__ bb, f32x4 (&acc)[4][2]) {
  constexpr int NK = K / 32;
  i32x4 ra0 = llvm_amdgcn_raw_buffer_load_i32x4(srdA, voA + kt * 64, 0, AUX);
  i32x4 ra1 = llvm_amdgcn_raw_buffer_load_i32x4(srdA, voA + 16 * K * 2 + kt * 64, 0, AUX);
  i32x4 ra2 = llvm_amdgcn_raw_buffer_load_i32x4(srdA, voA + 32 * K * 2 + kt * 64, 0, AUX);
  i32x4 ra3 = llvm_amdgcn_raw_buffer_load_i32x4(srdA, voA + 48 * K * 2 + kt * 64, 0, AUX);
  u16x8 b0 = *(const u16x8*)(bb + kt * 512);
  u16x8 b1 = *(const u16x8*)(bb + (NK + kt) * 512);
  bf16x8 fb0 = __builtin_bit_cast(bf16x8, b0);
  bf16x8 fb1 = __builtin_bit_cast(bf16x8, b1);
  bf16x8 fa0 = __builtin_bit_cast(bf16x8, ra0);
  bf16x8 fa1 = __builtin_bit_cast(bf16x8, ra1);
  bf16x8 fa2 = __builtin_bit_cast(bf16x8, ra2);
  bf16x8 fa3 = __builtin_bit_cast(bf16x8, ra3);
  acc[0][0] = __builtin_amdgcn_mfma_f32_16x16x32_bf16(fa0, fb0, acc[0][0], 0, 0, 0);
  acc[0][1] = __builtin_amdgcn_mfma_f32_16x16x32_bf16(fa0, fb1, acc[0][1], 0, 0, 0);
  acc[1][0] = __builtin_amdgcn_mfma_f32_16x16x32_bf16(fa1, fb0, acc[1][0], 0, 0, 0);
  acc[1][1] = __builtin_amdgcn_mfma_f32_16x16x32_bf16(fa1, fb1, acc[1][1], 0, 0, 0);
  acc[2][0] = __builtin_amdgcn_mfma_f32_16x16x32_bf16(fa2, fb0, acc[2][0], 0, 0, 0);
  acc[2][1] = __builtin_amdgcn_mfma_f32_16x16x32_bf16(fa2, fb1, acc[2][1], 0, 0, 0);
  acc[3][0] = __builtin_amdgcn_mfma_f32_16x16x32_bf16(fa3, fb0, acc[3][0], 0, 0, 0);
  acc[3][1] = __builtin_amdgcn_mfma_f32_16x16x32_bf16(fa3, fb1, acc[3][1], 0, 0, 0);
}

// C[256x32] = A[256xK] @ Bt(lds); tanh; bf16 stores. KHI splits aux domains.
// CROSS0: out0 via L3-coherent buffer stores (srdO0); else plain ptr out0p.
template<int K, int KHI, int AUXLO, int AUXHI, bool CROSS0, bool DUAL>
__device__ __forceinline__ void gemm_tick(const i32x4& srdA, const u16* __restrict__ Blds,
    const float* __restrict__ bias, int M0, int N0, int tid,
    const i32x4& srdO0, u16* __restrict__ out0p, int ld0,
    u16* __restrict__ out1, int ld1) {
  constexpr int NK = K / 32;
  const int lane = tid & 63, w = tid >> 6, q = lane >> 4, l16 = lane & 15;
  const int voA = ((M0 + w * 64 + l16) * K + q * 8) * 2;
  const u16* bb = Blds + lane * 8;

  f32x4 acc[4][2];
#pragma unroll
  for (int i = 0; i < 4; ++i)
#pragma unroll
    for (int j = 0; j < 2; ++j) acc[i][j] = (f32x4){0.f, 0.f, 0.f, 0.f};

#pragma unroll 4
  for (int kt = 0; kt < KHI / 32; ++kt) kstep<K, AUXLO>(srdA, voA, kt, bb, acc);
  if constexpr (KHI < K) {
#pragma unroll 4
    for (int kt = KHI / 32; kt < NK; ++kt) kstep<K, AUXHI>(srdA, voA, kt, bb, acc);
  }

  const float bs0 = bias[N0 + l16];
  const float bs1 = bias[N0 + 16 + l16];
#pragma unroll
  for (int i = 0; i < 4; ++i) {
#pragma unroll
    for (int rr = 0; rr < 4; ++rr) {
      const int row = M0 + w * 64 + i * 16 + q * 4 + rr;
      const u16 v0 = f2bf(fast_tanh(acc[i][0][rr] + bs0));
      const u16 v1 = f2bf(fast_tanh(acc[i][1][rr] + bs1));
      if (CROSS0) {
        llvm_amdgcn_raw_buffer_store_i16(v0, srdO0, (row * ld0 + N0 + l16) * 2, 0, AUX_L3);
        llvm_amdgcn_raw_buffer_store_i16(v1, srdO0, (row * ld0 + N0 + 16 + l16) * 2, 0, AUX_L3);
      } else {
        out0p[(size_t)row * ld0 + N0 + l16] = v0;
        out0p[(size_t)row * ld0 + N0 + 16 + l16] = v1;
      }
      if (DUAL) {
        out1[(size_t)row * ld1 + N0 + l16] = v0;
        out1[(size_t)row * ld1 + N0 + 16 + l16] = v1;
      }
    }
  }
}

__global__ __launch_bounds__(NTHR, 1)
void rnn_kernel(const int* __restrict__ inputs, const float* __restrict__ emb,
    const float* __restrict__ W0, const float* __restrict__ U0, const float* __restrict__ b0,
    const float* __restrict__ W1, const float* __restrict__ U1, const float* __restrict__ b1,
    const float* __restrict__ Wout, const float* __restrict__ bout,
    float* __restrict__ out,
    u16* __restrict__ Wt0, u16* __restrict__ Wt1,
    u16* __restrict__ A0, u16* __restrict__ A1, int* __restrict__ bar)
{
  extern __shared__ u16 lds[];
  cg::grid_group grid = cg::this_grid();
  const int tid = threadIdx.x, bid = blockIdx.x;
  const size_t HN0 = (size_t)BB * K0, HN1 = (size_t)BB * K1;

  // ---- startup phase 1 (bid-distributed): weights, emb(0), zero states, zero barrier ----
  const int gstart = bid * NTHR + tid;
  wfill<K0, 512>(Wt0, W0, U0, gstart);
  wfill<K1, 1024>(Wt1, W1, U1, gstart);
  for (int g = gstart; g < BB * EE / 8; g += NBLK * NTHR) {   // emb(0) -> A0 buf0 emb-half
    const int b = g >> 6, seg = g & 63;
    const int idx = inputs[b * TT];
    const f32x4* s = (const f32x4*)(emb + (size_t)idx * EE + seg * 8);
    f32x4 f0 = s[0], f1 = s[1];
    u16x8 o;
#pragma unroll
    for (int j = 0; j < 4; ++j) { o[j] = f2bf(f0[j]); o[j + 4] = f2bf(f1[j]); }
    *(u16x8*)(A0 + (size_t)b * K0 + seg * 8) = o;
  }
  {
    const u16x8 z = {0, 0, 0, 0, 0, 0, 0, 0};
    for (int g = gstart; g < BB * 1024 / 8; g += NBLK * NTHR) {
      const int b = g >> 7, seg = g & 127;
      *(u16x8*)(A0 + (size_t)b * K0 + 512 + seg * 8) = z;     // h0(-1) = 0
      *(u16x8*)(A1 + (size_t)b * K1 + 1024 + seg * 8) = z;    // h1(-1) = 0
    }
  }
  if (bid == 0) for (int i = tid; i < BAR_INTS; i += NTHR) bar[i] = 0;
  grid.sync();   // one heavy sync: all startup data + zeroed barrier visible everywhere

  // ---- roles from the TRUE XCD (s_getreg XCC_ID) + roster slot ----
  __shared__ int s_xcc, s_slot;
  if (tid == 0) {
    int xcc = __builtin_amdgcn_s_getreg((7 << 11) | 20) & 7;   // hwreg(XCC_ID, 0, 8)
    s_xcc = xcc;
    s_slot = atomicAdd(&bar[ROSTER_SLOT + xcc], 1);
  }
  __syncthreads();
  const int xcc = s_xcc;
  const int flavor = (xcc >= 4);
  const int rg = xcc & 3;
  const int cgrp = s_slot & 31;
  const int M0 = rg * 256, N0 = cgrp * 32;

  // ---- B stripe -> LDS ----
  {
    const int Kf = flavor ? K1 : K0;
    const u16x8* s = (const u16x8*)((flavor ? Wt1 : Wt0) + (size_t)cgrp * 32 * Kf);
    u16x8* d = (u16x8*)lds;
    const int nv = 32 * Kf / 8;
    for (int i = tid; i < nv; i += NTHR) d[i] = s[i];
  }
  __syncthreads();

  // ---- tick loop: flavor0 step tk, flavor1 step tk-1; custom barrier each tick ----
  for (int tk = 0; tk <= TT; ++tk) {
    const int tgt = tk + 1;
    if (!flavor) {
      if (tk < TT) {
        i32x4 srdA = make_srd(A0 + (size_t)(tk & 1) * HN0);
        i32x4 srdO0 = make_srd(A1 + (size_t)(tk & 1) * HN1);          // h0' -> layer1 (cross-XCD, L3)
        u16* o1 = A0 + (size_t)((tk + 1) & 1) * HN0 + 512;            // h0 recurrent (XCD-local, L2)
        gemm_tick<K0, K0, AUX_L2, AUX_L2, true, true>(
            srdA, lds, b0, M0, N0, tid, srdO0, (u16*)nullptr, K1, o1, K0);
      }
      if (tk < TT - 1) {   // stage emb(tk+1): 8 rows of my rg slice, plain stores (L2-local)
        u16* dst = A0 + (size_t)((tk + 1) & 1) * HN0;
        const int fid = rg * 32 + cgrp;
        const int row = fid * 8 + (tid >> 5);
        const int c = (tid & 31) * 16;
        const int idx = inputs[row * TT + tk + 1];
        const f32x4* s = (const f32x4*)(emb + (size_t)idx * EE + c);
        f32x4 f0 = s[0], f1 = s[1], f2 = s[2], f3 = s[3];
        u16x8 oa, ob;
#pragma unroll
        for (int j = 0; j < 4; ++j) {
          oa[j] = f2bf(f0[j]); oa[j + 4] = f2bf(f1[j]);
          ob[j] = f2bf(f2[j]); ob[j + 4] = f2bf(f3[j]);
        }
        *(u16x8*)(dst + (size_t)row * K0 + c) = oa;
        *(u16x8*)(dst + (size_t)row * K0 + c + 8) = ob;
      }
    } else {
      if (tk >= 1) {
        i32x4 srdA = make_srd(A1 + (size_t)((tk - 1) & 1) * HN1);
        u16* o0 = A1 + (size_t)(tk & 1) * HN1 + 1024;                 // h1 recurrent (XCD-local)
        // h0' half (kt<32): L3-coherent; h1 half: local L2
        gemm_tick<K1, 1024, AUX_L3, AUX_L2, false, false>(
            srdA, lds, b1, M0, N0, tid, srdA, o0, K1, (u16*)nullptr, 0);
      }
    }

    // ---- barrier: arrive (flag store) -> block0 polls -> epoch broadcast ----
    __syncthreads();   // compiler emits s_waitcnt vmcnt(0) before s_barrier: stores drained
    if (tid == 0)
      __hip_atomic_store(&bar[bid], tgt, __ATOMIC_RELAXED, __HIP_MEMORY_SCOPE_AGENT);
    if (bid == 0) {
      int v;
      do {
        v = __hip_atomic_load(&bar[tid], __ATOMIC_RELAXED, __HIP_MEMORY_SCOPE_AGENT);
      } while (!__all(v >= tgt));
      __syncthreads();
      if (tid == 0)
        __hip_atomic_store(&bar[EPOCH_SLOT], tgt, __ATOMIC_RELAXED, __HIP_MEMORY_SCOPE_AGENT);
    }
    if (tid == 0) {
      while (__hip_atomic_load(&bar[EPOCH_SLOT], __ATOMIC_RELAXED, __HIP_MEMORY_SCOPE_AGENT) < tgt)
        __builtin_amdgcn_s_sleep(2);
    }
    __syncthreads();
    asm volatile("" ::: "memory");
  }

  grid.sync();   // heavy sync: flush/merge all L2s before cross-XCD output read

  // ---- output: sigmoid(h1(255) @ Wout + bout); h1 final in A1 buf0 h1-half ----
  if (bid < 16) {
    const u16* hf = A1 + 1024;
    const int w = tid >> 6, lane = tid & 63;
    int m = (bid * 4 + w) * 16;
    for (int rr = 0; rr < 16; ++rr, ++m) {
      const u16x8* hv = (const u16x8*)(hf + (size_t)m * K1 + lane * 16);
      u16x8 lo = hv[0], hi = hv[1];
      const f32x4* wv = (const f32x4*)(Wout + lane * 16);
      f32x4 w0 = wv[0], w1 = wv[1], w2 = wv[2], w3 = wv[3];
      float s = 0.f;
#pragma unroll
      for (int j = 0; j < 4; ++j) {
        s += bf2f(lo[j]) * w0[j];
        s += bf2f(lo[j + 4]) * w1[j];
        s += bf2f(hi[j]) * w2[j];
        s += bf2f(hi[j + 4]) * w3[j];
      }
#pragma unroll
      for (int off = 32; off > 0; off >>= 1) s += __shfl_down(s, off);
      if (lane == 0) out[m] = 1.f / (1.f + expf(-(s + bout[0])));
    }
  }
}

extern "C" void kernel_launch(void* const* d_in, const int* in_sizes, int n_in,
                              void* d_out, int out_size, void* d_ws, size_t ws_size,
                              hipStream_t stream)
{
  (void)in_sizes; (void)n_in; (void)out_size; (void)ws_size;
  const int*   inputs = (const int*)d_in[0];
  const float* emb    = (const float*)d_in[1];
  const float* W0     = (const float*)d_in[2];
  const float* U0     = (const float*)d_in[3];
  const float* b0     = (const float*)d_in[4];
  const float* W1     = (const float*)d_in[5];
  const float* U1     = (const float*)d_in[6];
  const float* b1     = (const float*)d_in[7];
  const float* Wout   = (const float*)d_in[8];
  const float* bout   = (const float*)d_in[9];
  float* out = (float*)d_out;

  u16* Wt0 = (u16*)d_ws;
  u16* Wt1 = Wt0 + (size_t)1024 * K0;
  u16* A0  = Wt1 + (size_t)1024 * K1;
  u16* A1  = A0 + (size_t)2 * 1024 * K0;
  int* bar = (int*)(A1 + (size_t)2 * 1024 * K1);

  static int lds_set = 0;
  if (!lds_set) {
    hipFuncSetAttribute((const void*)rnn_kernel,
                        hipFuncAttributeMaxDynamicSharedMemorySize, LDS_BYTES);
    lds_set = 1;
  }

  void* args[] = { &inputs, &emb, &W0, &U0, &b0, &W1, &U1, &b1, &Wout, &bout,
                   &out, &Wt0, &Wt1, &A0, &A1, &bar };
  hipLaunchCooperativeKernel((void*)rnn_kernel, dim3(NBLK), dim3(NTHR), args, LDS_BYTES, stream);
}

// Round 5
// 7388.643 us; speedup vs baseline: 2.1674x; 1.2560x over previous
//
#include <hip/hip_runtime.h>
#include <hip/hip_cooperative_groups.h>
#include <math.h>

namespace cg = cooperative_groups;

typedef unsigned short u16;
typedef __bf16 bf16x8 __attribute__((ext_vector_type(8)));
typedef float f32x4 __attribute__((ext_vector_type(4)));
typedef unsigned short u16x8 __attribute__((ext_vector_type(8)));
typedef int i32x4 __attribute__((ext_vector_type(4)));

#define NBLK 256
#define NTHR 256
#define BB 1024
#define TT 256
#define EE 512
#define UU 1024
#define K0 1536          // A0 row: [emb(512) | h0(1024)]
#define K1 2048          // A1 row: [h0'(1024) | h1(1024)]
#define NK0 48           // K0/32
#define NK1 64           // K1/32
#define HN0 ((size_t)BB * K0)
#define HN1 ((size_t)BB * K1)
#define LDS_BYTES 131072 // proven size: 2 frag-cols (L1: 2*64*512*2B = 128 KB)

// bar layout (ints)
#define ROSTER_BASE 0            // [0..7] per-XCD block count
#define FLAG_BASE 32             // 8 * 256 arrival flags
#define EPOCH_BASE (32 + 2048)   // 8 epochs, 32-int stride
#define BAR_INTS 2560

#define AUX_SC0 1        // bypass L1, served by local L2

__device__ i32x4 llvm_amdgcn_raw_buffer_load_i32x4(i32x4 srsrc, int voffset, int soffset,
                                                   int aux) __asm("llvm.amdgcn.raw.buffer.load.v4i32");

__device__ __forceinline__ i32x4 make_srd(const void* p) {
  union { const void* p; int i[2]; } u; u.p = p;
  i32x4 r; r.x = u.i[0]; r.y = u.i[1]; r.z = -1; r.w = 0x00020000;
  return r;
}

__device__ __forceinline__ u16 f2bf(float f) {
  unsigned u = __builtin_bit_cast(unsigned, f);
  u += 0x7fffu + ((u >> 16) & 1u);
  return (u16)(u >> 16);
}
__device__ __forceinline__ float bf2f(u16 h) {
  return __builtin_bit_cast(float, ((unsigned)h) << 16);
}
__device__ __forceinline__ float fast_tanh(float x) {
  x = fminf(fmaxf(x, -15.f), 15.f);
  float e = __expf(2.f * x);
  return (e - 1.f) / (e + 1.f);
}

// weight transpose + MFMA-fragment swizzle (r2/r3-verified layout):
// elem g = (cb*NK + kt)*64 + lane (8 u16 each); value = Wfull[k][n],
// n = cb*16 + (lane&15), k = kt*32 + (lane>>4)*8 + e
template<int K, int KLOW>
__device__ __forceinline__ void wfill(u16* __restrict__ Wt,
    const float* __restrict__ Wl, const float* __restrict__ Wh, int gstart) {
  constexpr int NK = K / 32;
  constexpr int NG = 1024 * K / 8;
  for (int g = gstart; g < NG; g += NBLK * NTHR) {
    const int lane = g & 63;
    const int r = g >> 6;
    const int kt = r % NK;
    const int cb = r / NK;
    const int n = cb * 16 + (lane & 15);
    const int kb = kt * 32 + (lane >> 4) * 8;
    u16x8 o;
#pragma unroll
    for (int e = 0; e < 8; ++e) {
      const int k = kb + e;
      const float v = (k < KLOW) ? Wl[(size_t)k * UU + n] : Wh[(size_t)(k - KLOW) * UU + n];
      o[e] = f2bf(v);
    }
    *(u16x8*)(Wt + (size_t)g * 8) = o;
  }
}

// XCD-local barrier from r3-proven primitives: agent-scope flags + leader + epoch.
// Deadlock-proof: waits for measured nx arrivals; guarded polls bail instead of hanging.
__device__ __forceinline__ void xbar(int* __restrict__ bar, int xcc, int slot, int nx,
                                     int tgt, int tid) {
  __syncthreads();   // all waves' stores drained (vmcnt0) before arrival
  if (tid < 64) {
    if (tid == 0)
      __hip_atomic_store(&bar[FLAG_BASE + xcc * 256 + slot], tgt,
                         __ATOMIC_RELAXED, __HIP_MEMORY_SCOPE_AGENT);
    if (slot == 0) {
      for (int base = 0; base < nx; base += 64) {
        const int i = base + tid;
        const bool act = (i < nx);
        int guard = 0;
        bool done = false;
        do {
          int v = act ? __hip_atomic_load(&bar[FLAG_BASE + xcc * 256 + i],
                                          __ATOMIC_RELAXED, __HIP_MEMORY_SCOPE_AGENT)
                      : tgt;
          done = __all(v >= tgt) != 0;
        } while (!done && ++guard < 300000);
      }
      if (tid == 0)
        __hip_atomic_store(&bar[EPOCH_BASE + xcc * 32], tgt,
                           __ATOMIC_RELAXED, __HIP_MEMORY_SCOPE_AGENT);
    } else if (tid == 0) {
      int guard = 0;
      while (__hip_atomic_load(&bar[EPOCH_BASE + xcc * 32],
                               __ATOMIC_RELAXED, __HIP_MEMORY_SCOPE_AGENT) < tgt
             && ++guard < 600000)
        __builtin_amdgcn_s_sleep(8);
    }
  }
  __syncthreads();
}

// C[128x64] = A[128xK] @ B-stripe; bA = frag-cols 0,1 (LDS or global), bB = frag-cols 2,3
template<int K>
__device__ __forceinline__ void gemm2(const i32x4& srdA, int voA,
    const u16* __restrict__ bA, const u16* __restrict__ bB, int lane,
    f32x4 (&acc)[2][4]) {
  constexpr int NK = K / 32;
#pragma unroll 4
  for (int kt = 0; kt < NK; ++kt) {
    i32x4 a0 = llvm_amdgcn_raw_buffer_load_i32x4(srdA, voA + kt * 64, 0, AUX_SC0);
    i32x4 a1 = llvm_amdgcn_raw_buffer_load_i32x4(srdA, voA + 16 * K * 2 + kt * 64, 0, AUX_SC0);
    u16x8 b0 = *(const u16x8*)(bA + (size_t)(0 * NK + kt) * 512 + lane * 8);
    u16x8 b1 = *(const u16x8*)(bA + (size_t)(1 * NK + kt) * 512 + lane * 8);
    u16x8 b2 = *(const u16x8*)(bB + (size_t)(0 * NK + kt) * 512 + lane * 8);
    u16x8 b3 = *(const u16x8*)(bB + (size_t)(1 * NK + kt) * 512 + lane * 8);
    bf16x8 fa0 = __builtin_bit_cast(bf16x8, a0);
    bf16x8 fa1 = __builtin_bit_cast(bf16x8, a1);
    bf16x8 fb0 = __builtin_bit_cast(bf16x8, b0);
    bf16x8 fb1 = __builtin_bit_cast(bf16x8, b1);
    bf16x8 fb2 = __builtin_bit_cast(bf16x8, b2);
    bf16x8 fb3 = __builtin_bit_cast(bf16x8, b3);
    acc[0][0] = __builtin_amdgcn_mfma_f32_16x16x32_bf16(fa0, fb0, acc[0][0], 0, 0, 0);
    acc[0][1] = __builtin_amdgcn_mfma_f32_16x16x32_bf16(fa0, fb1, acc[0][1], 0, 0, 0);
    acc[0][2] = __builtin_amdgcn_mfma_f32_16x16x32_bf16(fa0, fb2, acc[0][2], 0, 0, 0);
    acc[0][3] = __builtin_amdgcn_mfma_f32_16x16x32_bf16(fa0, fb3, acc[0][3], 0, 0, 0);
    acc[1][0] = __builtin_amdgcn_mfma_f32_16x16x32_bf16(fa1, fb0, acc[1][0], 0, 0, 0);
    acc[1][1] = __builtin_amdgcn_mfma_f32_16x16x32_bf16(fa1, fb1, acc[1][1], 0, 0, 0);
    acc[1][2] = __builtin_amdgcn_mfma_f32_16x16x32_bf16(fa1, fb2, acc[1][2], 0, 0, 0);
    acc[1][3] = __builtin_amdgcn_mfma_f32_16x16x32_bf16(fa1, fb3, acc[1][3], 0, 0, 0);
  }
}

// layer-0 job jl (0..15): stage emb(tk+1) for rows jl*8..+8, then h0'(tk) GEMM
__device__ __forceinline__ void do_l0(int tk, int xcc, int jl, bool uselds,
    const u16* __restrict__ ldsb, const u16* __restrict__ Wt0,
    const int* __restrict__ inputs, const float* __restrict__ emb,
    const float* __restrict__ b0, u16* __restrict__ A0, u16* __restrict__ A1,
    int tid)
{
  const int lane = tid & 63, w = tid >> 6, q = lane >> 4, l16 = lane & 15;
  const int c0 = jl * 64;
  if (tk < TT - 1) {
    const int grow = xcc * 128 + jl * 8 + (tid >> 5);
    const int c = (tid & 31) * 16;
    const int idx = inputs[grow * TT + tk + 1];
    const f32x4* s = (const f32x4*)(emb + (size_t)idx * EE + c);
    f32x4 f0 = s[0], f1 = s[1], f2 = s[2], f3 = s[3];
    u16x8 oa, ob;
#pragma unroll
    for (int j = 0; j < 4; ++j) {
      oa[j] = f2bf(f0[j]); oa[j + 4] = f2bf(f1[j]);
      ob[j] = f2bf(f2[j]); ob[j + 4] = f2bf(f3[j]);
    }
    u16* dst = A0 + (size_t)((tk + 1) & 1) * HN0 + (size_t)grow * K0 + c;
    *(u16x8*)dst = oa;
    *(u16x8*)(dst + 8) = ob;
  }
  if (tk < TT) {
    f32x4 acc[2][4];
#pragma unroll
    for (int i = 0; i < 2; ++i)
#pragma unroll
      for (int n = 0; n < 4; ++n) acc[i][n] = (f32x4){0.f, 0.f, 0.f, 0.f};
    i32x4 srdA = make_srd(A0 + (size_t)(tk & 1) * HN0);
    const int voA = ((xcc * 128 + w * 32 + l16) * K0 + q * 8) * 2;
    const u16* bB = Wt0 + (size_t)(c0 / 16 + 2) * NK0 * 512;
    if (uselds) gemm2<K0>(srdA, voA, ldsb, bB, lane, acc);
    else        gemm2<K0>(srdA, voA, Wt0 + (size_t)(c0 / 16) * NK0 * 512, bB, lane, acc);
    u16* d1 = A1 + (size_t)(tk & 1) * HN1;              // h0' -> layer-1 input (same XCD)
    u16* d2 = A0 + (size_t)((tk + 1) & 1) * HN0 + 512;  // h0 recurrent
#pragma unroll
    for (int n = 0; n < 4; ++n) {
      const int col = c0 + n * 16 + l16;
      const float bs = b0[col];
#pragma unroll
      for (int i = 0; i < 2; ++i) {
#pragma unroll
        for (int rr = 0; rr < 4; ++rr) {
          const int grow = xcc * 128 + w * 32 + i * 16 + q * 4 + rr;
          const u16 v = f2bf(fast_tanh(acc[i][n][rr] + bs));
          d1[(size_t)grow * K1 + col] = v;
          d2[(size_t)grow * K0 + col] = v;
        }
      }
    }
  }
}

// layer-1 job jl (0..15): h1(tk-1) GEMM
__device__ __forceinline__ void do_l1(int tk, int xcc, int jl, bool uselds,
    const u16* __restrict__ ldsb, const u16* __restrict__ Wt1,
    const float* __restrict__ b1, u16* __restrict__ A1, int tid)
{
  const int lane = tid & 63, w = tid >> 6, q = lane >> 4, l16 = lane & 15;
  const int c0 = jl * 64;
  f32x4 acc[2][4];
#pragma unroll
  for (int i = 0; i < 2; ++i)
#pragma unroll
    for (int n = 0; n < 4; ++n) acc[i][n] = (f32x4){0.f, 0.f, 0.f, 0.f};
  i32x4 srdA = make_srd(A1 + (size_t)((tk - 1) & 1) * HN1);
  const int voA = ((xcc * 128 + w * 32 + l16) * K1 + q * 8) * 2;
  const u16* bB = Wt1 + (size_t)(c0 / 16 + 2) * NK1 * 512;
  if (uselds) gemm2<K1>(srdA, voA, ldsb, bB, lane, acc);
  else        gemm2<K1>(srdA, voA, Wt1 + (size_t)(c0 / 16) * NK1 * 512, bB, lane, acc);
  u16* d1 = A1 + (size_t)(tk & 1) * HN1 + 1024;         // h1 recurrent
#pragma unroll
  for (int n = 0; n < 4; ++n) {
    const int col = c0 + n * 16 + l16;
    const float bs = b1[col];
#pragma unroll
    for (int i = 0; i < 2; ++i) {
#pragma unroll
      for (int rr = 0; rr < 4; ++rr) {
        const int grow = xcc * 128 + w * 32 + i * 16 + q * 4 + rr;
        d1[(size_t)grow * K1 + col] = f2bf(fast_tanh(acc[i][n][rr] + bs));
      }
    }
  }
}

__global__ __launch_bounds__(NTHR, 1)
void rnn_kernel(const int* __restrict__ inputs, const float* __restrict__ emb,
    const float* __restrict__ W0, const float* __restrict__ U0, const float* __restrict__ b0,
    const float* __restrict__ W1, const float* __restrict__ U1, const float* __restrict__ b1,
    const float* __restrict__ Wout, const float* __restrict__ bout,
    float* __restrict__ out,
    u16* __restrict__ Wt0, u16* __restrict__ Wt1,
    u16* __restrict__ A0, u16* __restrict__ A1, int* __restrict__ bar)
{
  extern __shared__ u16 lds[];
  int* li = (int*)lds;
  cg::grid_group grid = cg::this_grid();
  const int tid = threadIdx.x, bid = blockIdx.x;

  // ---- startup (grid-distributed): weights, emb(0), zero states + barrier area ----
  const int gstart = bid * NTHR + tid;
  wfill<K0, 512>(Wt0, W0, U0, gstart);
  wfill<K1, 1024>(Wt1, W1, U1, gstart);
  for (int g = gstart; g < BB * EE / 8; g += NBLK * NTHR) {
    const int b = g >> 6, seg = g & 63;
    const int idx = inputs[b * TT];
    const f32x4* s = (const f32x4*)(emb + (size_t)idx * EE + seg * 8);
    f32x4 f0 = s[0], f1 = s[1];
    u16x8 o;
#pragma unroll
    for (int j = 0; j < 4; ++j) { o[j] = f2bf(f0[j]); o[j + 4] = f2bf(f1[j]); }
    *(u16x8*)(A0 + (size_t)b * K0 + seg * 8) = o;
  }
  {
    const u16x8 z = {0, 0, 0, 0, 0, 0, 0, 0};
    for (int g = gstart; g < BB * 1024 / 8; g += NBLK * NTHR) {
      const int b = g >> 7, seg = g & 127;
      *(u16x8*)(A0 + (size_t)b * K0 + 512 + seg * 8) = z;      // h0(-1) = 0
      *(u16x8*)(A1 + (size_t)b * K1 + 1024 + seg * 8) = z;     // h1(-1) = 0
    }
  }
  if (bid == 0) for (int i = tid; i < BAR_INTS; i += NTHR) bar[i] = 0;
  grid.sync();

  // ---- roster: true XCD + slot; second sync publishes per-XCD counts ----
  if (tid == 0) {
    const int xc = __builtin_amdgcn_s_getreg((7 << 11) | 20) & 7;   // HW_REG_XCC_ID
    li[0] = xc;
    li[1] = atomicAdd(&bar[ROSTER_BASE + xc], 1);
  }
  __syncthreads();
  const int xcc = li[0], slot = li[1];
  __syncthreads();
  grid.sync();
  if (tid == 0)
    li[0] = __hip_atomic_load(&bar[ROSTER_BASE + xcc],
                              __ATOMIC_RELAXED, __HIP_MEMORY_SCOPE_AGENT);
  __syncthreads();
  const int nx = li[0];
  __syncthreads();

  // ---- primary job's first 2 frag-cols -> LDS ----
  if (slot < 32) {
    const bool pL0 = slot < 16;
    const int cb = (pL0 ? slot : slot - 16) * 4;
    const int NKp = pL0 ? NK0 : NK1;
    const u16x8* s = (const u16x8*)((pL0 ? Wt0 : Wt1) + (size_t)cb * NKp * 512);
    const int nv = 2 * NKp * 64;
    u16x8* d = (u16x8*)lds;
    for (int i = tid; i < nv; i += NTHR) d[i] = s[i];
  }
  __syncthreads();

  // ---- tick loop: jobs 0..15 = layer0 stripes, 16..31 = layer1 stripes (lagged) ----
  for (int tk = 0; tk <= TT; ++tk) {
    for (int job = slot; job < 32; job += nx) {
      const bool uselds = (job == slot);
      if (job < 16) do_l0(tk, xcc, job, uselds, lds, Wt0, inputs, emb, b0, A0, A1, tid);
      else if (tk >= 1) do_l1(tk, xcc, job - 16, uselds, lds, Wt1, b1, A1, tid);
    }
    xbar(bar, xcc, slot, nx, tk + 1, tid);
  }

  // ---- output (slot 0 per XCD): sigmoid(h1(255) @ Wout + bout) for 128 local rows ----
  if (slot == 0) {
    const int lane = tid & 63, w = tid >> 6;
    i32x4 srdH = make_srd(A1);
    const f32x4* wv = (const f32x4*)(Wout + lane * 16);
    f32x4 w0 = wv[0], w1 = wv[1], w2 = wv[2], w3 = wv[3];
    for (int rr = 0; rr < 32; ++rr) {
      const int grow = xcc * 128 + w * 32 + rr;
      const int vo = (grow * K1 + 1024 + lane * 16) * 2;
      i32x4 hv0 = llvm_amdgcn_raw_buffer_load_i32x4(srdH, vo, 0, AUX_SC0);
      i32x4 hv1 = llvm_amdgcn_raw_buffer_load_i32x4(srdH, vo + 16, 0, AUX_SC0);
      u16x8 lo = __builtin_bit_cast(u16x8, hv0);
      u16x8 hi = __builtin_bit_cast(u16x8, hv1);
      float s = 0.f;
#pragma unroll
      for (int j = 0; j < 4; ++j) {
        s += bf2f(lo[j]) * w0[j];
        s += bf2f(lo[j + 4]) * w1[j];
        s += bf2f(hi[j]) * w2[j];
        s += bf2f(hi[j + 4]) * w3[j];
      }
#pragma unroll
      for (int off = 32; off > 0; off >>= 1) s += __shfl_down(s, off);
      if (lane == 0) out[grow] = 1.f / (1.f + expf(-(s + bout[0])));
    }
  }
}

extern "C" void kernel_launch(void* const* d_in, const int* in_sizes, int n_in,
                              void* d_out, int out_size, void* d_ws, size_t ws_size,
                              hipStream_t stream)
{
  (void)in_sizes; (void)n_in; (void)out_size; (void)ws_size;
  const int*   inputs = (const int*)d_in[0];
  const float* emb    = (const float*)d_in[1];
  const float* W0     = (const float*)d_in[2];
  const float* U0     = (const float*)d_in[3];
  const float* b0     = (const float*)d_in[4];
  const float* W1     = (const float*)d_in[5];
  const float* U1     = (const float*)d_in[6];
  const float* b1     = (const float*)d_in[7];
  const float* Wout   = (const float*)d_in[8];
  const float* bout   = (const float*)d_in[9];
  float* out = (float*)d_out;

  // ws (u16): Wt0 [1024*K0], Wt1 [1024*K1], A0 [2][1024*K0], A1 [2][1024*K1], bar
  u16* Wt0 = (u16*)d_ws;
  u16* Wt1 = Wt0 + (size_t)1024 * K0;
  u16* A0  = Wt1 + (size_t)1024 * K1;
  u16* A1  = A0 + (size_t)2 * 1024 * K0;
  int* bar = (int*)(A1 + (size_t)2 * 1024 * K1);

  static int lds_set = 0;
  if (!lds_set) {
    hipFuncSetAttribute((const void*)rnn_kernel,
                        hipFuncAttributeMaxDynamicSharedMemorySize, LDS_BYTES);
    lds_set = 1;
  }

  void* args[] = { &inputs, &emb, &W0, &U0, &b0, &W1, &U1, &b1, &Wout, &bout,
                   &out, &Wt0, &Wt1, &A0, &A1, &bar };
  hipLaunchCooperativeKernel((void*)rnn_kernel, dim3(NBLK), dim3(NTHR), args, LDS_BYTES, stream);
}